// Round 2
// baseline (106.558 us; speedup 1.0000x reference)
//
#include <hip/hip_runtime.h>
#include <hip/hip_bf16.h>
#include <stdint.h>

// SimCLR loss, n=8192, d=128, T=0.07.
//  k_normalize: fp32 features -> row-L2-normalized bf16 fn (ws)
//  k_simexp:    E_part[slice][row] = sum_{j in slice} exp2((dot_ij - 1)*s)
//               MFMA bf16; B-panel staged in LDS via global_load_lds (dbuf,
//               XOR-swizzled both sides); diagonal included, removed later.
//  k_finalize:  per row term = 1/T + ln(E - exp2((selfdot-1)*s)) - posdot/T;
//               block-partial -> atomicAdd(out, partial/N). d_out pre-memset.

#define N_ROWS 8192
#define DIM    128
#define HALF_N 4096
#define N_SLICES 32
#define JCOLS (N_ROWS / N_SLICES)      // 256 cols per slice
#define NT (JCOLS / 16)                // 16 j-tiles per wave
#define ROWS_PER_BLOCK 256             // 4 waves * 64 rows

static constexpr float INV_T = 14.285714285714286f;   // 1/0.07
static constexpr float SCALE = 20.60992915555662f;    // log2(e)/0.07

typedef __attribute__((ext_vector_type(8))) short short8;   // 8 bf16
typedef __attribute__((ext_vector_type(4))) float f32x4;

#if __has_builtin(__builtin_amdgcn_exp2f)
__device__ inline float fast_exp2(float x) { return __builtin_amdgcn_exp2f(x); }
#else
__device__ inline float fast_exp2(float x) { return exp2f(x); }
#endif

__device__ inline float bf_lo(uint32_t u) { return __uint_as_float(u << 16); }
__device__ inline float bf_hi(uint32_t u) { return __uint_as_float(u & 0xFFFF0000u); }
__device__ inline uint16_t f2bf(float x) {
    uint32_t u = __float_as_uint(x);
    return (uint16_t)((u + 0x7FFFu + ((u >> 16) & 1u)) >> 16);   // RNE
}

// async global->LDS, 16B per lane; LDS dest is wave-uniform base (+lane*16 by HW)
__device__ inline void load_lds16(const void* g, void* l) {
    __builtin_amdgcn_global_load_lds(
        (const __attribute__((address_space(1))) uint32_t*)g,
        (__attribute__((address_space(3))) uint32_t*)l, 16, 0, 0);
}

// ---------------- kernel 1: row L2-normalize, fp32 -> bf16 ----------------
__global__ __launch_bounds__(256) void k_normalize(const float* __restrict__ f,
                                                   uint16_t* __restrict__ fn) {
    int wid  = (blockIdx.x * blockDim.x + threadIdx.x) >> 6;   // one wave per row
    int lane = threadIdx.x & 63;
    const float2* src = (const float2*)(f + (size_t)wid * DIM);
    float2 v = src[lane];
    float ss = v.x * v.x + v.y * v.y;
    #pragma unroll
    for (int m = 1; m < 64; m <<= 1) ss += __shfl_xor(ss, m, 64);
    float inv = rsqrtf(ss);
    ushort2 o;
    o.x = f2bf(v.x * inv);
    o.y = f2bf(v.y * inv);
    ((ushort2*)(fn + (size_t)wid * DIM))[lane] = o;
}

// ---------------- kernel 2: fused sim + exp-sum (MFMA) ----------------
// Grid (N_ROWS/256, N_SLICES); block = 4 waves, each owns 64 rows.
// Per jt: one 16-col B tile (4 KiB) staged in LDS, shared by all 4 waves.
__global__ __launch_bounds__(256, 4) void k_simexp(const uint16_t* __restrict__ fn,
                                                   float* __restrict__ E_part) {
    __shared__ __align__(16) uint16_t Bl[2][16 * DIM];   // 2 x 4 KiB
    const int tid   = threadIdx.x;
    const int lane  = tid & 63;
    const int w     = tid >> 6;
    const int ib    = blockIdx.x * ROWS_PER_BLOCK + w * 64;
    const int slice = blockIdx.y;
    const int lr = lane & 15;
    const int lk = lane >> 4;

    const short8* fn8 = (const short8*)fn;

    // A fragments pinned in registers: row ib+mt*16+lr, dims kc*32+lk*8..+8
    short8 Af[4][4];
    #pragma unroll
    for (int mt = 0; mt < 4; ++mt)
        #pragma unroll
        for (int kc = 0; kc < 4; ++kc)
            Af[mt][kc] = fn8[(size_t)(ib + mt * 16 + lr) * 16 + kc * 4 + lk];

    float es[4][4];
    #pragma unroll
    for (int mt = 0; mt < 4; ++mt)
        #pragma unroll
        for (int r = 0; r < 4; ++r) es[mt][r] = 0.0f;

    // --- staging (write side): thread t covers LDS phys bytes [16t,16t+16).
    // Logical layout [col][dim]; swizzle: phys = logical ^ ((col&7)<<4).
    // So thread t fetches global chunk (t&15)^(col&7) of col t>>4.
    const int scol = tid >> 4;
    const int schk = (tid & 15) ^ (scol & 7);
    const short8* sgp = fn8 + (size_t)(slice * JCOLS + scol) * 16 + schk;
    uint16_t* wb[2] = { &Bl[0][0] + w * 512, &Bl[1][0] + w * 512 };  // wave-uniform

    // --- read side: col lr, chunk kc*4+lk -> phys byte lr*256 + ((kc*4+lk)^(lr&7))*16
    const int rbase = lr * 256;
    const int rsw   = lr & 7;

    load_lds16(sgp, wb[0]);   // stage tile 0

    for (int jt = 0; jt < NT; ++jt) {
        __syncthreads();                                   // stage(cur) landed
        if (jt + 1 < NT)
            load_lds16(sgp + (size_t)(jt + 1) * 256, wb[(jt + 1) & 1]);
        const char* bp = (const char*)&Bl[jt & 1][0];
        short8 Bf[4];
        #pragma unroll
        for (int kc = 0; kc < 4; ++kc)
            Bf[kc] = *(const short8*)(bp + rbase + ((((kc << 2) | lk) ^ rsw) << 4));
        #pragma unroll
        for (int mt = 0; mt < 4; ++mt) {
            f32x4 acc = {0.0f, 0.0f, 0.0f, 0.0f};
            #pragma unroll
            for (int kc = 0; kc < 4; ++kc)
                acc = __builtin_amdgcn_mfma_f32_16x16x32_bf16(Af[mt][kc], Bf[kc], acc, 0, 0, 0);
            #pragma unroll
            for (int r = 0; r < 4; ++r)
                es[mt][r] += fast_exp2(fmaf(acc[r], SCALE, -SCALE));
        }
    }

    // C/D layout: col = lane&15, row = lk*4 + r. Sum over 16 col-lanes.
    #pragma unroll
    for (int mt = 0; mt < 4; ++mt)
        #pragma unroll
        for (int r = 0; r < 4; ++r) {
            float v = es[mt][r];
            v += __shfl_xor(v, 1, 64);
            v += __shfl_xor(v, 2, 64);
            v += __shfl_xor(v, 4, 64);
            v += __shfl_xor(v, 8, 64);
            if (lr == 0)
                E_part[(size_t)slice * N_ROWS + ib + mt * 16 + lk * 4 + r] = v;
        }
}

// ---------------- kernel 3: finalize + mean (atomic) ----------------
__global__ __launch_bounds__(256) void k_finalize(const uint16_t* __restrict__ fn,
                                                  const float* __restrict__ E_part,
                                                  float* __restrict__ out) {
    __shared__ float sm[4];
    int wid  = (blockIdx.x * blockDim.x + threadIdx.x) >> 6;   // one wave per row
    int lane = threadIdx.x & 63;
    int partner = (wid + HALF_N) & (N_ROWS - 1);
    const uint32_t* fr = (const uint32_t*)(fn + (size_t)wid * DIM);
    const uint32_t* pr = (const uint32_t*)(fn + (size_t)partner * DIM);
    uint32_t a = fr[lane], p = pr[lane];
    float a0 = bf_lo(a), a1 = bf_hi(a);
    float p0 = bf_lo(p), p1 = bf_hi(p);
    float sd = a0 * a0 + a1 * a1;       // self dot  (diagonal recompute)
    float pd = a0 * p0 + a1 * p1;       // positive-pair dot
    #pragma unroll
    for (int m = 1; m < 64; m <<= 1) {
        sd += __shfl_xor(sd, m, 64);
        pd += __shfl_xor(pd, m, 64);
    }
    float e = (lane < N_SLICES) ? E_part[(size_t)lane * N_ROWS + wid] : 0.0f;
    #pragma unroll
    for (int m = 1; m < 64; m <<= 1) e += __shfl_xor(e, m, 64);
    if (lane == 0) {
        float ep = e - fast_exp2(fmaf(sd, SCALE, -SCALE));   // remove diagonal
        sm[threadIdx.x >> 6] = INV_T + logf(ep) - pd * INV_T;
    }
    __syncthreads();
    if (threadIdx.x == 0)
        atomicAdd(out, (sm[0] + sm[1] + sm[2] + sm[3]) * (1.0f / N_ROWS));
}

extern "C" void kernel_launch(void* const* d_in, const int* in_sizes, int n_in,
                              void* d_out, int out_size, void* d_ws, size_t ws_size,
                              hipStream_t stream) {
    const float* feat = (const float*)d_in[0];
    float* out = (float*)d_out;

    // ws: fn (bf16, 2 MiB) | E_part (f32, 32*8192*4 = 1 MiB)
    uint16_t* fn  = (uint16_t*)d_ws;
    float* E_part = (float*)((char*)d_ws + (size_t)N_ROWS * DIM * 2);

    hipMemsetAsync(out, 0, sizeof(float), stream);
    k_normalize<<<dim3(N_ROWS / 4), dim3(256), 0, stream>>>(feat, fn);
    k_simexp<<<dim3(N_ROWS / ROWS_PER_BLOCK, N_SLICES), dim3(256), 0, stream>>>(fn, E_part);
    k_finalize<<<dim3(N_ROWS / 4), dim3(256), 0, stream>>>(fn, E_part, out);
}